// Round 10
// baseline (57.406 us; speedup 1.0000x reference)
//
#include <hip/hip_runtime.h>
#include <hip/hip_cooperative_groups.h>
#include <math.h>

namespace cg = cooperative_groups;

#define NGAUSS 2000
#define IMW 128
#define IMH 128
#define NPIX (IMW*IMH)
#define PSTRIDE 12
#define NW 16                     // waves per block
#define SEGSZ ((NGAUSS + NW - 1) / NW)   // 125 gaussians per wave-segment

__device__ inline float rdlane(float x, int l) {
    return __uint_as_float(__builtin_amdgcn_readlane(__float_as_uint(x), l));
}

// ---------------- single cooperative kernel: prep+rank | grid.sync | render ----
// Phase 1 (one wave per gaussian, waves 2000..4095 idle):
//   params to sorted[rank], layout (3 x float4):
//   [0] = { m2x, m2y, s_cull, q0s }   s_cull = lambda_min(Q) * log2(e)
//   [1] = { q1s, q2s, c0,    cr  }   qXs pre-scaled by -log2(e) for exp2
//   [2] = { cg,  cb,  depth, 0   }
// Phase 2 (block = 64x1 px tile, 16 waves split depth into 125-segments):
//   ballot-cull per 64-chunk (SoA stride-1 LDS), survivors broadcast via
//   v_readlane, partials combined in-LDS in depth order by wave 0.
//   Reference semantics: weight[0]=a_0; weight[n>=1]=a_n*(1-a_n)*prod_{k<n}(1-a_k)
__global__ __launch_bounds__(1024) void fused_kernel(
    const float* __restrict__ means3D, const float* __restrict__ covs3d,
    const float* __restrict__ colors, const float* __restrict__ opac,
    const float* __restrict__ Km, const float* __restrict__ Rm,
    const float* __restrict__ tv, float* __restrict__ sorted,
    float* __restrict__ out)
{
    extern __shared__ char ldsbuf[];
    float*  mxA  = (float*)ldsbuf;                 // [2048]
    float*  myA  = mxA + 2048;
    float*  sA   = myA + 2048;
    float*  q0A  = sA + 2048;
    float4* sp2  = (float4*)(q0A + 2048);          // [2000*2]
    float4* pOut = sp2 + 2*NGAUSS;                 // [NW*64]

    int tid  = threadIdx.x;
    int lane = tid & 63;
    int w    = tid >> 6;
    int bid  = blockIdx.x;

    // ================= phase 1: prep + rank =================
    int i = bid * NW + w;
    if (i < NGAUSS) {
        float R0 = Rm[0], R1 = Rm[1], R2 = Rm[2];
        float R3 = Rm[3], R4 = Rm[4], R5 = Rm[5];
        float R6 = Rm[6], R7 = Rm[7], R8 = Rm[8];
        float t0 = tv[0], t1v = tv[1], t2 = tv[2];

        // rank: recompute depth_j inline (identical expression for i and j)
        float mx = means3D[3*i+0], my = means3D[3*i+1], mz = means3D[3*i+2];
        float di = fmaxf(R6*mx + R7*my + R8*mz + t2, 1.0f);
        int rank = 0;
        for (int j = lane; j < NGAUSS; j += 64) {
            float jx = means3D[3*j+0], jy = means3D[3*j+1], jz = means3D[3*j+2];
            float dj = fmaxf(R6*jx + R7*jy + R8*jz + t2, 1.0f);
            bool lt = (j != i) && ((dj < di) || (dj == di && j < i));  // stable
            rank += lt ? 1 : 0;
        }
        #pragma unroll
        for (int o = 32; o > 0; o >>= 1) rank += __shfl_down(rank, o, 64);
        rank = __shfl(rank, 0, 64);

        // prep (redundant on all lanes)
        float camx = R0*mx + R1*my + R2*mz + t0;
        float camy = R3*mx + R4*my + R5*mz + t1v;
        float camz = R6*mx + R7*my + R8*mz + t2;
        float depth = fmaxf(camz, 1.0f);
        bool valid = (depth > 1.0f) && (depth < 50.0f);

        float fx = Km[0], cx = Km[2], fy = Km[4], cy = Km[5];
        float invz = 1.0f / camz;
        float m2x = (fx*camx + cx*camz) * invz;
        float m2y = (fy*camy + cy*camz) * invz;
        float J00 = fx*invz, J02 = -fx*camx*invz*invz;
        float J11 = fy*invz, J12 = -fy*camy*invz*invz;

        float S0 = covs3d[9*i+0], S1 = covs3d[9*i+1], S2 = covs3d[9*i+2];
        float S3 = covs3d[9*i+3], S4 = covs3d[9*i+4], S5 = covs3d[9*i+5];
        float S6 = covs3d[9*i+6], S7 = covs3d[9*i+7], S8 = covs3d[9*i+8];

        float RS0 = R0*S0 + R1*S3 + R2*S6;
        float RS1 = R0*S1 + R1*S4 + R2*S7;
        float RS2 = R0*S2 + R1*S5 + R2*S8;
        float RS3 = R3*S0 + R4*S3 + R5*S6;
        float RS4 = R3*S1 + R4*S4 + R5*S7;
        float RS5 = R3*S2 + R4*S5 + R5*S8;
        float RS6 = R6*S0 + R7*S3 + R8*S6;
        float RS7 = R6*S1 + R7*S4 + R8*S7;
        float RS8 = R6*S2 + R7*S5 + R8*S8;

        float Sc0 = RS0*R0 + RS1*R1 + RS2*R2;
        float Sc1 = RS0*R3 + RS1*R4 + RS2*R5;
        float Sc2 = RS0*R6 + RS1*R7 + RS2*R8;
        float Sc3 = RS3*R0 + RS4*R1 + RS5*R2;
        float Sc4 = RS3*R3 + RS4*R4 + RS5*R5;
        float Sc5 = RS3*R6 + RS4*R7 + RS5*R8;
        float Sc6 = RS6*R0 + RS7*R1 + RS8*R2;
        float Sc7 = RS6*R3 + RS7*R4 + RS8*R5;
        float Sc8 = RS6*R6 + RS7*R7 + RS8*R8;

        float A00 = J00*Sc0 + J02*Sc6;
        float A01 = J00*Sc1 + J02*Sc7;
        float A02 = J00*Sc2 + J02*Sc8;
        float A10 = J11*Sc3 + J12*Sc6;
        float A11 = J11*Sc4 + J12*Sc7;
        float A12 = J11*Sc5 + J12*Sc8;

        float a = A00*J00 + A02*J02 + 1e-4f;
        float b = A01*J11 + A02*J12;
        float c = A10*J00 + A12*J02;
        float d = A11*J11 + A12*J12 + 1e-4f;

        float det = a*d - b*c;
        float invdet = 1.0f / det;
        float q0u = d*invdet;
        float q1u = -(b + c)*invdet;
        float q2u = a*invdet;
        // smallest eigenvalue of [[q0u, q1u/2],[q1u/2, q2u]] for conservative cull
        float mh = 0.5f*(q0u + q2u);
        float dh = 0.5f*(q0u - q2u);
        float oh = 0.5f*q1u;
        float lmin = mh - sqrtf(dh*dh + oh*oh);
        const float L2E = 1.4426950408889634f;
        float s_cull = lmin * L2E;
        float q0 = -q0u * L2E;
        float q1 = -q1u * L2E;
        float q2 = -q2u * L2E;
        float c0 = opac[i] * 0.15915494309189535f / sqrtf(det);
        if (!valid) { m2x = 0.f; m2y = 0.f; q0 = 0.f; q1 = 0.f; q2 = 0.f; c0 = 0.f; s_cull = 3.0e38f; }

        float cr = colors[3*i+0], cg = colors[3*i+1], cb = colors[3*i+2];
        if (lane < 3) {
            float4 v = (lane == 0) ? make_float4(m2x, m2y, s_cull, q0)
                     : (lane == 1) ? make_float4(q1, q2, c0, cr)
                                   : make_float4(cg, cb, depth, 0.f);
            ((float4*)(sorted + (size_t)rank*PSTRIDE))[lane] = v;
        }
    }

    cg::this_grid().sync();   // device-scope barrier + fence (sorted visible)

    // ================= phase 2: render =================
    int row  = bid >> 1;
    int xoff = (bid & 1) * 64;

    // stage all params once (coalesced)
    for (int g = tid; g < NGAUSS; g += 1024) {
        const float4* src = (const float4*)(sorted + (size_t)g*PSTRIDE);
        float4 v0 = src[0], v1 = src[1], v2 = src[2];
        mxA[g] = v0.x; myA[g] = v0.y; sA[g] = v0.z; q0A[g] = v0.w;
        sp2[g*2] = v1; sp2[g*2+1] = v2;
    }
    __syncthreads();

    float px = (float)(xoff + lane);
    float py = (float)row;
    float x0 = (float)xoff, x1 = x0 + 63.0f;

    float Cr = 0.f, Cg = 0.f, Cb = 0.f, T = 1.f;

    int segBase = w * SEGSZ;
    int segEnd  = segBase + SEGSZ; if (segEnd > NGAUSS) segEnd = NGAUSS;

    for (int cb = segBase; cb < segEnd; cb += 64) {
        int g = cb + lane;
        float cmx = 0.f, cmy = 0.f, cq0 = 0.f;
        bool keep = false;
        if (g < segEnd) {
            cmx = mxA[g]; cmy = myA[g]; cq0 = q0A[g];
            float cs = sA[g];
            float dxm = fmaxf(0.f, fmaxf(x0 - cmx, cmx - x1));
            float dym = fabsf(py - cmy);
            keep = cs * fmaf(dxm, dxm, dym*dym) <= 24.f;   // alpha >= c0*2^-24
        }
        float4 v1 = make_float4(0.f,0.f,0.f,0.f), v2 = v1;
        if (keep) { v1 = sp2[g*2]; v2 = sp2[g*2+1]; }
        unsigned long long mask = __ballot(keep);
        while (mask) {
            int b = __builtin_ctzll(mask);
            mask &= mask - 1;
            int gn = cb + b;
            float gmx = rdlane(cmx, b), gmy = rdlane(cmy, b), gq0 = rdlane(cq0, b);
            float gq1 = rdlane(v1.x, b), gq2 = rdlane(v1.y, b), gc0 = rdlane(v1.z, b);
            float gcr = rdlane(v1.w, b), gcg = rdlane(v2.x, b), gcb = rdlane(v2.y, b);
            float dy = py - gmy;
            float u1 = gq1 * dy;
            float dx = px - gmx;
            float e  = fmaf(fmaf(gq0, dx, u1), dx, (gq2*dy)*dy);
            float al = gc0 * exp2f(e);               // alpha
            float wgt = T * al;                      // T*alpha
            float sel = (gn == 0) ? 0.f : al;        // rank-0: weight = alpha exactly
            float f = fmaf(-sel, wgt, wgt);          // T*alpha*(1-alpha)
            Cr = fmaf(f, gcr, Cr);
            Cg = fmaf(f, gcg, Cg);
            Cb = fmaf(f, gcb, Cb);
            T -= wgt;                                // T *= (1-alpha)
        }
    }

    pOut[w*64 + lane] = make_float4(Cr, Cg, Cb, T);
    __syncthreads();

    // wave 0 composites the 16 depth-ordered partials for its 64 px
    if (tid < 64) {
        float cR = 0.f, cG = 0.f, cB = 0.f, tA = 1.f;
        #pragma unroll
        for (int s = 0; s < NW; ++s) {
            float4 v = pOut[s*64 + tid];
            cR = fmaf(tA, v.x, cR);
            cG = fmaf(tA, v.y, cG);
            cB = fmaf(tA, v.z, cB);
            tA *= v.w;
        }
        int p = row*IMW + xoff + tid;
        out[3*p+0] = cR; out[3*p+1] = cG; out[3*p+2] = cB;
    }
}

extern "C" void kernel_launch(void* const* d_in, const int* in_sizes, int n_in,
                              void* d_out, int out_size, void* d_ws, size_t ws_size,
                              hipStream_t stream)
{
    const float* means3D = (const float*)d_in[0];
    const float* covs3d  = (const float*)d_in[1];
    const float* colors  = (const float*)d_in[2];
    const float* opac    = (const float*)d_in[3];
    const float* Km      = (const float*)d_in[4];
    const float* Rm      = (const float*)d_in[5];
    const float* tv      = (const float*)d_in[6];

    float* sorted = (float*)d_ws;          // NGAUSS*12 floats = 96 KB
    float* outp   = (float*)d_out;

    size_t ldsBytes = 4*2048*sizeof(float)              // SoA cull arrays
                    + (size_t)2*NGAUSS*sizeof(float4)   // quads 1,2
                    + (size_t)NW*64*sizeof(float4);     // partials

    void* args[] = { (void*)&means3D, (void*)&covs3d, (void*)&colors,
                     (void*)&opac, (void*)&Km, (void*)&Rm, (void*)&tv,
                     (void*)&sorted, (void*)&outp };
    hipLaunchCooperativeKernel((const void*)fused_kernel,
                               dim3(NPIX/64), dim3(1024),
                               args, (unsigned int)ldsBytes, stream);
}

// Round 11
// 27.560 us; speedup vs baseline: 2.0830x; 2.0830x over previous
//
#include <hip/hip_runtime.h>
#include <math.h>

#define NGAUSS 2000
#define IMW 128
#define IMH 128
#define NPIX (IMW*IMH)
#define PSTRIDE 12
#define NW 16                     // waves per render block
#define SEGSZ ((NGAUSS + NW - 1) / NW)   // 125 gaussians per wave-segment

__device__ inline float rdlane(float x, int l) {
    return __uint_as_float(__builtin_amdgcn_readlane(__float_as_uint(x), l));
}

// ---------------- fused prep + stable rank sort + scatter ----------------
// One wave per gaussian. Param layout (per gaussian, 3 x float4):
//   [0] = { m2x, m2y, s_cull, q0s }   s_cull = lambda_min(Q) * log2(e)
//   [1] = { q1s, q2s, c0,    cr  }   qXs pre-scaled by -log2(e) for exp2
//   [2] = { cg,  cb,  depth, 0   }
__global__ __launch_bounds__(64) void preprank_kernel(
    const float* __restrict__ means3D, const float* __restrict__ covs3d,
    const float* __restrict__ colors, const float* __restrict__ opac,
    const float* __restrict__ Km, const float* __restrict__ Rm,
    const float* __restrict__ tv, float* __restrict__ sorted)
{
    int i = blockIdx.x;
    int lane = threadIdx.x;

    float R0 = Rm[0], R1 = Rm[1], R2 = Rm[2];
    float R3 = Rm[3], R4 = Rm[4], R5 = Rm[5];
    float R6 = Rm[6], R7 = Rm[7], R8 = Rm[8];
    float t0 = tv[0], t1v = tv[1], t2 = tv[2];

    // ---- rank: recompute depth_j inline (identical expression for i and j) ----
    float mx = means3D[3*i+0], my = means3D[3*i+1], mz = means3D[3*i+2];
    float di = fmaxf(R6*mx + R7*my + R8*mz + t2, 1.0f);
    int rank = 0;
    for (int j = lane; j < NGAUSS; j += 64) {
        float jx = means3D[3*j+0], jy = means3D[3*j+1], jz = means3D[3*j+2];
        float dj = fmaxf(R6*jx + R7*jy + R8*jz + t2, 1.0f);
        bool lt = (j != i) && ((dj < di) || (dj == di && j < i));  // stable, self-safe
        rank += lt ? 1 : 0;
    }
    #pragma unroll
    for (int o = 32; o > 0; o >>= 1) rank += __shfl_down(rank, o, 64);
    rank = __shfl(rank, 0, 64);

    // ---- prep (redundant on all lanes) ----
    float camx = R0*mx + R1*my + R2*mz + t0;
    float camy = R3*mx + R4*my + R5*mz + t1v;
    float camz = R6*mx + R7*my + R8*mz + t2;
    float depth = fmaxf(camz, 1.0f);
    bool valid = (depth > 1.0f) && (depth < 50.0f);

    float fx = Km[0], cx = Km[2], fy = Km[4], cy = Km[5];
    float invz = 1.0f / camz;
    float m2x = (fx*camx + cx*camz) * invz;
    float m2y = (fy*camy + cy*camz) * invz;
    float J00 = fx*invz, J02 = -fx*camx*invz*invz;
    float J11 = fy*invz, J12 = -fy*camy*invz*invz;

    float S0 = covs3d[9*i+0], S1 = covs3d[9*i+1], S2 = covs3d[9*i+2];
    float S3 = covs3d[9*i+3], S4 = covs3d[9*i+4], S5 = covs3d[9*i+5];
    float S6 = covs3d[9*i+6], S7 = covs3d[9*i+7], S8 = covs3d[9*i+8];

    float RS0 = R0*S0 + R1*S3 + R2*S6;
    float RS1 = R0*S1 + R1*S4 + R2*S7;
    float RS2 = R0*S2 + R1*S5 + R2*S8;
    float RS3 = R3*S0 + R4*S3 + R5*S6;
    float RS4 = R3*S1 + R4*S4 + R5*S7;
    float RS5 = R3*S2 + R4*S5 + R5*S8;
    float RS6 = R6*S0 + R7*S3 + R8*S6;
    float RS7 = R6*S1 + R7*S4 + R8*S7;
    float RS8 = R6*S2 + R7*S5 + R8*S8;

    float Sc0 = RS0*R0 + RS1*R1 + RS2*R2;
    float Sc1 = RS0*R3 + RS1*R4 + RS2*R5;
    float Sc2 = RS0*R6 + RS1*R7 + RS2*R8;
    float Sc3 = RS3*R0 + RS4*R1 + RS5*R2;
    float Sc4 = RS3*R3 + RS4*R4 + RS5*R5;
    float Sc5 = RS3*R6 + RS4*R7 + RS5*R8;
    float Sc6 = RS6*R0 + RS7*R1 + RS8*R2;
    float Sc7 = RS6*R3 + RS7*R4 + RS8*R5;
    float Sc8 = RS6*R6 + RS7*R7 + RS8*R8;

    float A00 = J00*Sc0 + J02*Sc6;
    float A01 = J00*Sc1 + J02*Sc7;
    float A02 = J00*Sc2 + J02*Sc8;
    float A10 = J11*Sc3 + J12*Sc6;
    float A11 = J11*Sc4 + J12*Sc7;
    float A12 = J11*Sc5 + J12*Sc8;

    float a = A00*J00 + A02*J02 + 1e-4f;
    float b = A01*J11 + A02*J12;
    float c = A10*J00 + A12*J02;
    float d = A11*J11 + A12*J12 + 1e-4f;

    float det = a*d - b*c;
    float invdet = 1.0f / det;
    float q0u = d*invdet;
    float q1u = -(b + c)*invdet;
    float q2u = a*invdet;
    // smallest eigenvalue of [[q0u, q1u/2],[q1u/2, q2u]] for conservative cull
    float mh = 0.5f*(q0u + q2u);
    float dh = 0.5f*(q0u - q2u);
    float oh = 0.5f*q1u;
    float lmin = mh - sqrtf(dh*dh + oh*oh);
    const float L2E = 1.4426950408889634f;
    float s_cull = lmin * L2E;
    float q0 = -q0u * L2E;
    float q1 = -q1u * L2E;
    float q2 = -q2u * L2E;
    float c0 = opac[i] * 0.15915494309189535f / sqrtf(det);
    if (!valid) { m2x = 0.f; m2y = 0.f; q0 = 0.f; q1 = 0.f; q2 = 0.f; c0 = 0.f; s_cull = 3.0e38f; }

    float cr = colors[3*i+0], cg = colors[3*i+1], cb = colors[3*i+2];
    if (lane < 3) {
        float4 v = (lane == 0) ? make_float4(m2x, m2y, s_cull, q0)
                 : (lane == 1) ? make_float4(q1, q2, c0, cr)
                               : make_float4(cg, cb, depth, 0.f);
        ((float4*)(sorted + (size_t)rank*PSTRIDE))[lane] = v;
    }
}

// ---------------- fused render: block = 64x1 px tile, 16 waves split depth ----
// Full-SoA LDS (10 stride-1 arrays, conflict-free). Every lane loads all 10
// params of its gaussian in the cull pass; survivor walk is pure VALU with
// v_readlane broadcasts, manually software-pipelined 2 deep.
// Reference semantics: weight[0]=a_0; weight[n>=1]=a_n*(1-a_n)*prod_{k<n}(1-a_k)
__global__ __launch_bounds__(1024) void render_fused(
    const float* __restrict__ sorted, float* __restrict__ out)
{
    extern __shared__ char ldsbuf[];
    float* mxA = (float*)ldsbuf;       // 10 SoA arrays of 2048 floats
    float* myA = mxA + 2048;
    float* sA  = myA + 2048;
    float* q0A = sA  + 2048;
    float* q1A = q0A + 2048;
    float* q2A = q1A + 2048;
    float* c0A = q2A + 2048;
    float* crA = c0A + 2048;
    float* cgA = crA + 2048;
    float* cbA = cgA + 2048;
    float4* pOut = (float4*)(cbA + 2048);   // [NW*64]

    int tid  = threadIdx.x;
    int lane = tid & 63;
    int w    = tid >> 6;
    int bid  = blockIdx.x;
    int row  = bid >> 1;
    int xoff = (bid & 1) * 64;

    // ---- stage all params once (coalesced read, stride-1 SoA writes) ----
    for (int g = tid; g < NGAUSS; g += 1024) {
        const float4* src = (const float4*)(sorted + (size_t)g*PSTRIDE);
        float4 v0 = src[0], v1 = src[1], v2 = src[2];
        mxA[g] = v0.x; myA[g] = v0.y; sA[g]  = v0.z; q0A[g] = v0.w;
        q1A[g] = v1.x; q2A[g] = v1.y; c0A[g] = v1.z; crA[g] = v1.w;
        cgA[g] = v2.x; cbA[g] = v2.y;
    }
    __syncthreads();

    float px = (float)(xoff + lane);
    float py = (float)row;
    float x0 = (float)xoff, x1 = x0 + 63.0f;

    float Cr = 0.f, Cg = 0.f, Cb = 0.f, T = 1.f;

    int segBase = w * SEGSZ;
    int segEnd  = segBase + SEGSZ; if (segEnd > NGAUSS) segEnd = NGAUSS;

    for (int cbb = segBase; cbb < segEnd; cbb += 64) {
        int g = cbb + lane;
        bool inb = g < segEnd;
        int gc = inb ? g : segBase;
        float cmx = mxA[gc], cmy = myA[gc], cs = sA[gc];
        float cq0 = q0A[gc], cq1 = q1A[gc], cq2 = q2A[gc];
        float cc0 = c0A[gc], ccr = crA[gc], ccg = cgA[gc], ccb = cbA[gc];
        bool keep = false;
        if (inb) {
            float dxm = fmaxf(0.f, fmaxf(x0 - cmx, cmx - x1));
            float dym = fabsf(py - cmy);
            keep = cs * fmaf(dxm, dxm, dym*dym) <= 24.f;   // alpha >= c0*2^-24
        }
        unsigned long long mask = __ballot(keep);
        if (!mask) continue;

        int b0 = __builtin_ctzll(mask);
        float p_mx = rdlane(cmx, b0), p_my = rdlane(cmy, b0);
        float p_q0 = rdlane(cq0, b0), p_q1 = rdlane(cq1, b0), p_q2 = rdlane(cq2, b0);
        float p_c0 = rdlane(cc0, b0), p_cr = rdlane(ccr, b0);
        float p_cg = rdlane(ccg, b0), p_cb = rdlane(ccb, b0);
        int gn = cbb + b0;

        while (true) {
            unsigned long long m2 = mask & (mask - 1);
            int b2 = m2 ? __builtin_ctzll(m2) : 0;
            // prefetch next survivor's params (hidden under current eval)
            float n_mx = rdlane(cmx, b2), n_my = rdlane(cmy, b2);
            float n_q0 = rdlane(cq0, b2), n_q1 = rdlane(cq1, b2), n_q2 = rdlane(cq2, b2);
            float n_c0 = rdlane(cc0, b2), n_cr = rdlane(ccr, b2);
            float n_cg = rdlane(ccg, b2), n_cb = rdlane(ccb, b2);
            int gn2 = cbb + b2;
            // eval current survivor
            float dy = py - p_my;
            float dx = px - p_mx;
            float e  = fmaf(fmaf(p_q0, dx, p_q1*dy), dx, (p_q2*dy)*dy);
            float al = p_c0 * exp2f(e);              // alpha
            float wgt = T * al;                      // T*alpha
            float sel = (gn == 0) ? 0.f : al;        // rank-0: weight = alpha exactly
            float f = fmaf(-sel, wgt, wgt);          // T*alpha*(1-alpha)
            Cr = fmaf(f, p_cr, Cr);
            Cg = fmaf(f, p_cg, Cg);
            Cb = fmaf(f, p_cb, Cb);
            T -= wgt;                                // T *= (1-alpha)
            mask = m2;
            if (!mask) break;
            p_mx = n_mx; p_my = n_my; p_q0 = n_q0; p_q1 = n_q1; p_q2 = n_q2;
            p_c0 = n_c0; p_cr = n_cr; p_cg = n_cg; p_cb = n_cb; gn = gn2;
        }
    }

    pOut[w*64 + lane] = make_float4(Cr, Cg, Cb, T);
    __syncthreads();

    // ---- wave 0 composites the 16 depth-ordered partials for its 64 px ----
    if (tid < 64) {
        float cR = 0.f, cG = 0.f, cB = 0.f, tA = 1.f;
        #pragma unroll
        for (int s = 0; s < NW; ++s) {
            float4 v = pOut[s*64 + tid];
            cR = fmaf(tA, v.x, cR);
            cG = fmaf(tA, v.y, cG);
            cB = fmaf(tA, v.z, cB);
            tA *= v.w;
        }
        int p = row*IMW + xoff + tid;
        out[3*p+0] = cR; out[3*p+1] = cG; out[3*p+2] = cB;
    }
}

extern "C" void kernel_launch(void* const* d_in, const int* in_sizes, int n_in,
                              void* d_out, int out_size, void* d_ws, size_t ws_size,
                              hipStream_t stream)
{
    const float* means3D = (const float*)d_in[0];
    const float* covs3d  = (const float*)d_in[1];
    const float* colors  = (const float*)d_in[2];
    const float* opac    = (const float*)d_in[3];
    const float* Km      = (const float*)d_in[4];
    const float* Rm      = (const float*)d_in[5];
    const float* tv      = (const float*)d_in[6];

    float* sorted = (float*)d_ws;   // NGAUSS*12 floats = 96 KB

    preprank_kernel<<<NGAUSS, 64, 0, stream>>>(
        means3D, covs3d, colors, opac, Km, Rm, tv, sorted);

    size_t ldsBytes = (size_t)10*2048*sizeof(float)     // SoA param arrays
                    + (size_t)NW*64*sizeof(float4);     // partials
    render_fused<<<NPIX/64, 1024, ldsBytes, stream>>>(sorted, (float*)d_out);
}

// Round 12
// 25.772 us; speedup vs baseline: 2.2275x; 1.0694x over previous
//
#include <hip/hip_runtime.h>
#include <math.h>

#define NGAUSS 2000
#define IMW 128
#define IMH 128
#define NPIX (IMW*IMH)
#define NW 16                     // waves per render block
#define SEGSZ ((NGAUSS + NW - 1) / NW)   // 125 gaussians per wave-segment

__device__ inline float rdlane(float x, int l) {
    return __uint_as_float(__builtin_amdgcn_readlane(__float_as_uint(x), l));
}

// ---------------- fused prep + stable rank sort + SoA scatter ----------------
// One wave per gaussian. SoA output: soa[k*2000 + rank], k =
//   0:m2x 1:m2y 2:s_cull 3:q0s 4:q1s 5:q2s 6:c0 7:cr 8:cg 9:cb
// (qXs pre-scaled by -log2(e) for exp2; s_cull = lambda_min(Q)*log2(e))
__global__ __launch_bounds__(64) void preprank_kernel(
    const float* __restrict__ means3D, const float* __restrict__ covs3d,
    const float* __restrict__ colors, const float* __restrict__ opac,
    const float* __restrict__ Km, const float* __restrict__ Rm,
    const float* __restrict__ tv, float* __restrict__ soa)
{
    int i = blockIdx.x;
    int lane = threadIdx.x;

    float R0 = Rm[0], R1 = Rm[1], R2 = Rm[2];
    float R3 = Rm[3], R4 = Rm[4], R5 = Rm[5];
    float R6 = Rm[6], R7 = Rm[7], R8 = Rm[8];
    float t0 = tv[0], t1v = tv[1], t2 = tv[2];

    // ---- rank via ballot+popcount (wave-uniform result, no reduce needed) ----
    float mx = means3D[3*i+0], my = means3D[3*i+1], mz = means3D[3*i+2];
    float di = fmaxf(R6*mx + R7*my + R8*mz + t2, 1.0f);
    int rank = 0;
    for (int base = 0; base < 2048; base += 64) {
        int j = base + lane;
        int jc = (j < NGAUSS) ? j : 0;                 // clamp OOB load
        float jx = means3D[3*jc+0], jy = means3D[3*jc+1], jz = means3D[3*jc+2];
        float dj = fmaxf(R6*jx + R7*jy + R8*jz + t2, 1.0f);
        bool lt = (j < NGAUSS) && (j != i) &&
                  ((dj < di) || (dj == di && j < i));  // stable tie-break
        rank += (int)__popcll(__ballot(lt));
    }

    // ---- prep (redundant on all lanes) ----
    float camx = R0*mx + R1*my + R2*mz + t0;
    float camy = R3*mx + R4*my + R5*mz + t1v;
    float camz = R6*mx + R7*my + R8*mz + t2;
    float depth = fmaxf(camz, 1.0f);
    bool valid = (depth > 1.0f) && (depth < 50.0f);

    float fx = Km[0], cx = Km[2], fy = Km[4], cy = Km[5];
    float invz = 1.0f / camz;
    float m2x = (fx*camx + cx*camz) * invz;
    float m2y = (fy*camy + cy*camz) * invz;
    float J00 = fx*invz, J02 = -fx*camx*invz*invz;
    float J11 = fy*invz, J12 = -fy*camy*invz*invz;

    float S0 = covs3d[9*i+0], S1 = covs3d[9*i+1], S2 = covs3d[9*i+2];
    float S3 = covs3d[9*i+3], S4 = covs3d[9*i+4], S5 = covs3d[9*i+5];
    float S6 = covs3d[9*i+6], S7 = covs3d[9*i+7], S8 = covs3d[9*i+8];

    float RS0 = R0*S0 + R1*S3 + R2*S6;
    float RS1 = R0*S1 + R1*S4 + R2*S7;
    float RS2 = R0*S2 + R1*S5 + R2*S8;
    float RS3 = R3*S0 + R4*S3 + R5*S6;
    float RS4 = R3*S1 + R4*S4 + R5*S7;
    float RS5 = R3*S2 + R4*S5 + R5*S8;
    float RS6 = R6*S0 + R7*S3 + R8*S6;
    float RS7 = R6*S1 + R7*S4 + R8*S7;
    float RS8 = R6*S2 + R7*S5 + R8*S8;

    float Sc0 = RS0*R0 + RS1*R1 + RS2*R2;
    float Sc1 = RS0*R3 + RS1*R4 + RS2*R5;
    float Sc2 = RS0*R6 + RS1*R7 + RS2*R8;
    float Sc3 = RS3*R0 + RS4*R1 + RS5*R2;
    float Sc4 = RS3*R3 + RS4*R4 + RS5*R5;
    float Sc5 = RS3*R6 + RS4*R7 + RS5*R8;
    float Sc6 = RS6*R0 + RS7*R1 + RS8*R2;
    float Sc7 = RS6*R3 + RS7*R4 + RS8*R5;
    float Sc8 = RS6*R6 + RS7*R7 + RS8*R8;

    float A00 = J00*Sc0 + J02*Sc6;
    float A01 = J00*Sc1 + J02*Sc7;
    float A02 = J00*Sc2 + J02*Sc8;
    float A10 = J11*Sc3 + J12*Sc6;
    float A11 = J11*Sc4 + J12*Sc7;
    float A12 = J11*Sc5 + J12*Sc8;

    float a = A00*J00 + A02*J02 + 1e-4f;
    float b = A01*J11 + A02*J12;
    float c = A10*J00 + A12*J02;
    float d = A11*J11 + A12*J12 + 1e-4f;

    float det = a*d - b*c;
    float invdet = 1.0f / det;
    float q0u = d*invdet;
    float q1u = -(b + c)*invdet;
    float q2u = a*invdet;
    // smallest eigenvalue of [[q0u, q1u/2],[q1u/2, q2u]] for conservative cull
    float mh = 0.5f*(q0u + q2u);
    float dh = 0.5f*(q0u - q2u);
    float oh = 0.5f*q1u;
    float lmin = mh - sqrtf(dh*dh + oh*oh);
    const float L2E = 1.4426950408889634f;
    float s_cull = lmin * L2E;
    float q0 = -q0u * L2E;
    float q1 = -q1u * L2E;
    float q2 = -q2u * L2E;
    float c0 = opac[i] * 0.15915494309189535f / sqrtf(det);
    if (!valid) { m2x = 0.f; m2y = 0.f; q0 = 0.f; q1 = 0.f; q2 = 0.f; c0 = 0.f; s_cull = 3.0e38f; }

    float cr = colors[3*i+0], cg = colors[3*i+1], cb = colors[3*i+2];
    float v = (lane == 0) ? m2x
            : (lane == 1) ? m2y
            : (lane == 2) ? s_cull
            : (lane == 3) ? q0
            : (lane == 4) ? q1
            : (lane == 5) ? q2
            : (lane == 6) ? c0
            : (lane == 7) ? cr
            : (lane == 8) ? cg
                          : cb;
    if (lane < 10) soa[lane*NGAUSS + rank] = v;
}

// ---------------- render: reg-resident segment, no LDS staging ----------------
// Block = 64x1 px tile, 16 waves split depth into 125-gaussian segments.
// Each lane HOLDS the params of its segment's gaussians (2 chunks x 10 regs,
// stride-1 coalesced SoA loads). Cull on own regs -> ballot -> survivors
// broadcast via v_readlane from holder lane. 16 partials combined in 16KB LDS.
// Reference semantics: weight[0]=a_0; weight[n>=1]=a_n*(1-a_n)*prod_{k<n}(1-a_k)
__global__ __launch_bounds__(1024) void render_fused(
    const float* __restrict__ soa, float* __restrict__ out)
{
    __shared__ float4 pOut[NW*64];

    int tid  = threadIdx.x;
    int lane = tid & 63;
    int w    = tid >> 6;
    int bid  = blockIdx.x;
    int row  = bid >> 1;
    int xoff = (bid & 1) * 64;

    float px = (float)(xoff + lane);
    float py = (float)row;
    float x0 = (float)xoff, x1 = x0 + 63.0f;

    float Cr = 0.f, Cg = 0.f, Cb = 0.f, T = 1.f;

    int segBase = w * SEGSZ;

    // ---- load own-lane params: chunk A (lane 0..63), chunk B (lane 64..124) ----
    int gA = segBase + lane;
    bool vB = (64 + lane) < SEGSZ;
    int gB = vB ? (segBase + 64 + lane) : segBase;
    float A0 = soa[0*NGAUSS+gA], A1 = soa[1*NGAUSS+gA], A2 = soa[2*NGAUSS+gA];
    float A3 = soa[3*NGAUSS+gA], A4 = soa[4*NGAUSS+gA], A5 = soa[5*NGAUSS+gA];
    float A6 = soa[6*NGAUSS+gA], A7 = soa[7*NGAUSS+gA], A8 = soa[8*NGAUSS+gA];
    float A9 = soa[9*NGAUSS+gA];
    float B0 = soa[0*NGAUSS+gB], B1 = soa[1*NGAUSS+gB], B2 = soa[2*NGAUSS+gB];
    float B3 = soa[3*NGAUSS+gB], B4 = soa[4*NGAUSS+gB], B5 = soa[5*NGAUSS+gB];
    float B6 = soa[6*NGAUSS+gB], B7 = soa[7*NGAUSS+gB], B8 = soa[8*NGAUSS+gB];
    float B9 = soa[9*NGAUSS+gB];

    // ---- chunk A ----
    {
        float dxm = fmaxf(0.f, fmaxf(x0 - A0, A0 - x1));
        float dym = fabsf(py - A1);
        bool keep = A2 * fmaf(dxm, dxm, dym*dym) <= 24.f;   // alpha >= c0*2^-24
        unsigned long long mask = __ballot(keep);
        while (mask) {
            int b = __builtin_ctzll(mask);
            mask &= mask - 1;
            int gn = segBase + b;
            float gmx = rdlane(A0,b), gmy = rdlane(A1,b);
            float gq0 = rdlane(A3,b), gq1 = rdlane(A4,b), gq2 = rdlane(A5,b);
            float gc0 = rdlane(A6,b), gcr = rdlane(A7,b);
            float gcg = rdlane(A8,b), gcb = rdlane(A9,b);
            float dy = py - gmy;
            float dx = px - gmx;
            float e  = fmaf(fmaf(gq0, dx, gq1*dy), dx, (gq2*dy)*dy);
            float al = gc0 * exp2f(e);               // alpha
            float wgt = T * al;                      // T*alpha
            float sel = (gn == 0) ? 0.f : al;        // rank-0: weight = alpha exactly
            float f = fmaf(-sel, wgt, wgt);          // T*alpha*(1-alpha)
            Cr = fmaf(f, gcr, Cr);
            Cg = fmaf(f, gcg, Cg);
            Cb = fmaf(f, gcb, Cb);
            T -= wgt;                                // T *= (1-alpha)
        }
    }
    // ---- chunk B ----
    {
        float dxm = fmaxf(0.f, fmaxf(x0 - B0, B0 - x1));
        float dym = fabsf(py - B1);
        bool keep = vB && (B2 * fmaf(dxm, dxm, dym*dym) <= 24.f);
        unsigned long long mask = __ballot(keep);
        while (mask) {
            int b = __builtin_ctzll(mask);
            mask &= mask - 1;
            float gmx = rdlane(B0,b), gmy = rdlane(B1,b);
            float gq0 = rdlane(B3,b), gq1 = rdlane(B4,b), gq2 = rdlane(B5,b);
            float gc0 = rdlane(B6,b), gcr = rdlane(B7,b);
            float gcg = rdlane(B8,b), gcb = rdlane(B9,b);
            float dy = py - gmy;
            float dx = px - gmx;
            float e  = fmaf(fmaf(gq0, dx, gq1*dy), dx, (gq2*dy)*dy);
            float al = gc0 * exp2f(e);
            float wgt = T * al;
            float f = fmaf(-al, wgt, wgt);           // gn>0 always here
            Cr = fmaf(f, gcr, Cr);
            Cg = fmaf(f, gcg, Cg);
            Cb = fmaf(f, gcb, Cb);
            T -= wgt;
        }
    }

    pOut[w*64 + lane] = make_float4(Cr, Cg, Cb, T);
    __syncthreads();

    // ---- wave 0 composites the 16 depth-ordered partials for its 64 px ----
    if (tid < 64) {
        float cR = 0.f, cG = 0.f, cB = 0.f, tA = 1.f;
        #pragma unroll
        for (int s = 0; s < NW; ++s) {
            float4 v = pOut[s*64 + tid];
            cR = fmaf(tA, v.x, cR);
            cG = fmaf(tA, v.y, cG);
            cB = fmaf(tA, v.z, cB);
            tA *= v.w;
        }
        int p = row*IMW + xoff + tid;
        out[3*p+0] = cR; out[3*p+1] = cG; out[3*p+2] = cB;
    }
}

extern "C" void kernel_launch(void* const* d_in, const int* in_sizes, int n_in,
                              void* d_out, int out_size, void* d_ws, size_t ws_size,
                              hipStream_t stream)
{
    const float* means3D = (const float*)d_in[0];
    const float* covs3d  = (const float*)d_in[1];
    const float* colors  = (const float*)d_in[2];
    const float* opac    = (const float*)d_in[3];
    const float* Km      = (const float*)d_in[4];
    const float* Rm      = (const float*)d_in[5];
    const float* tv      = (const float*)d_in[6];

    float* soa = (float*)d_ws;   // 10 arrays x NGAUSS floats = 80 KB

    preprank_kernel<<<NGAUSS, 64, 0, stream>>>(
        means3D, covs3d, colors, opac, Km, Rm, tv, soa);
    render_fused<<<NPIX/64, 1024, 0, stream>>>(soa, (float*)d_out);
}

// Round 13
// 23.791 us; speedup vs baseline: 2.4129x; 1.0832x over previous
//
#include <hip/hip_runtime.h>
#include <math.h>

#define NGAUSS 2000
#define IMW 128
#define IMH 128
#define NPIX (IMW*IMH)
#define NW 16                     // waves per block (both kernels)
#define SEGSZ ((NGAUSS + NW - 1) / NW)   // 125 gaussians per wave-segment
#define PREPBLK (NGAUSS / NW)            // 125 preprank blocks

__device__ inline float rdlane(float x, int l) {
    return __uint_as_float(__builtin_amdgcn_readlane(__float_as_uint(x), l));
}

// ---------------- fused prep + stable rank sort + SoA scatter ----------------
// 125 blocks x 16 waves; wave w of block b owns gaussian i = b*16+w.
// Block stages all 2000 depths in LDS (coalesced), ranks come from LDS reads.
// SoA output: soa[k*2000 + rank], k =
//   0:m2x 1:m2y 2:s_cull 3:q0s 4:q1s 5:q2s 6:c0 7:cr 8:cg 9:cb
// (qXs pre-scaled by -log2(e) for exp2; s_cull = lambda_min(Q)*log2(e))
__global__ __launch_bounds__(1024) void preprank_kernel(
    const float* __restrict__ means3D, const float* __restrict__ covs3d,
    const float* __restrict__ colors, const float* __restrict__ opac,
    const float* __restrict__ Km, const float* __restrict__ Rm,
    const float* __restrict__ tv, float* __restrict__ soa)
{
    __shared__ float sdep[2048];

    int tid  = threadIdx.x;
    int lane = tid & 63;
    int w    = tid >> 6;
    int i    = blockIdx.x * NW + w;        // this wave's gaussian

    float R0 = Rm[0], R1 = Rm[1], R2 = Rm[2];
    float R3 = Rm[3], R4 = Rm[4], R5 = Rm[5];
    float R6 = Rm[6], R7 = Rm[7], R8 = Rm[8];
    float t0 = tv[0], t1v = tv[1], t2 = tv[2];

    // ---- stage all depths in LDS (coalesced) ----
    for (int g = tid; g < 2048; g += 1024) {
        float dep = 3.0e38f;                // pad > all real depths
        if (g < NGAUSS) {
            float jx = means3D[3*g+0], jy = means3D[3*g+1], jz = means3D[3*g+2];
            dep = fmaxf(R6*jx + R7*jy + R8*jz + t2, 1.0f);
        }
        sdep[g] = dep;
    }
    __syncthreads();

    // ---- rank via LDS + ballot/popc (wave-uniform result) ----
    float di = sdep[i];
    int rank = 0;
    for (int base = 0; base < 2048; base += 64) {
        int j = base + lane;
        float dj = sdep[j];
        bool lt = (j != i) && ((dj < di) || (dj == di && j < i));  // stable; pad never lt
        rank += (int)__popcll(__ballot(lt));
    }

    // ---- prep (redundant on all lanes of the wave) ----
    float mx = means3D[3*i+0], my = means3D[3*i+1], mz = means3D[3*i+2];
    float camx = R0*mx + R1*my + R2*mz + t0;
    float camy = R3*mx + R4*my + R5*mz + t1v;
    float camz = R6*mx + R7*my + R8*mz + t2;
    float depth = fmaxf(camz, 1.0f);
    bool valid = (depth > 1.0f) && (depth < 50.0f);

    float fx = Km[0], cx = Km[2], fy = Km[4], cy = Km[5];
    float invz = 1.0f / camz;
    float m2x = (fx*camx + cx*camz) * invz;
    float m2y = (fy*camy + cy*camz) * invz;
    float J00 = fx*invz, J02 = -fx*camx*invz*invz;
    float J11 = fy*invz, J12 = -fy*camy*invz*invz;

    float S0 = covs3d[9*i+0], S1 = covs3d[9*i+1], S2 = covs3d[9*i+2];
    float S3 = covs3d[9*i+3], S4 = covs3d[9*i+4], S5 = covs3d[9*i+5];
    float S6 = covs3d[9*i+6], S7 = covs3d[9*i+7], S8 = covs3d[9*i+8];

    float RS0 = R0*S0 + R1*S3 + R2*S6;
    float RS1 = R0*S1 + R1*S4 + R2*S7;
    float RS2 = R0*S2 + R1*S5 + R2*S8;
    float RS3 = R3*S0 + R4*S3 + R5*S6;
    float RS4 = R3*S1 + R4*S4 + R5*S7;
    float RS5 = R3*S2 + R4*S5 + R5*S8;
    float RS6 = R6*S0 + R7*S3 + R8*S6;
    float RS7 = R6*S1 + R7*S4 + R8*S7;
    float RS8 = R6*S2 + R7*S5 + R8*S8;

    float Sc0 = RS0*R0 + RS1*R1 + RS2*R2;
    float Sc1 = RS0*R3 + RS1*R4 + RS2*R5;
    float Sc2 = RS0*R6 + RS1*R7 + RS2*R8;
    float Sc3 = RS3*R0 + RS4*R1 + RS5*R2;
    float Sc4 = RS3*R3 + RS4*R4 + RS5*R5;
    float Sc5 = RS3*R6 + RS4*R7 + RS5*R8;
    float Sc6 = RS6*R0 + RS7*R1 + RS8*R2;
    float Sc7 = RS6*R3 + RS7*R4 + RS8*R5;
    float Sc8 = RS6*R6 + RS7*R7 + RS8*R8;

    float A00 = J00*Sc0 + J02*Sc6;
    float A01 = J00*Sc1 + J02*Sc7;
    float A02 = J00*Sc2 + J02*Sc8;
    float A10 = J11*Sc3 + J12*Sc6;
    float A11 = J11*Sc4 + J12*Sc7;
    float A12 = J11*Sc5 + J12*Sc8;

    float a = A00*J00 + A02*J02 + 1e-4f;
    float b = A01*J11 + A02*J12;
    float c = A10*J00 + A12*J02;
    float d = A11*J11 + A12*J12 + 1e-4f;

    float det = a*d - b*c;
    float invdet = 1.0f / det;
    float q0u = d*invdet;
    float q1u = -(b + c)*invdet;
    float q2u = a*invdet;
    // smallest eigenvalue of [[q0u, q1u/2],[q1u/2, q2u]] for conservative cull
    float mh = 0.5f*(q0u + q2u);
    float dh = 0.5f*(q0u - q2u);
    float oh = 0.5f*q1u;
    float lmin = mh - sqrtf(dh*dh + oh*oh);
    const float L2E = 1.4426950408889634f;
    float s_cull = lmin * L2E;
    float q0 = -q0u * L2E;
    float q1 = -q1u * L2E;
    float q2 = -q2u * L2E;
    float c0 = opac[i] * 0.15915494309189535f / sqrtf(det);
    if (!valid) { m2x = 0.f; m2y = 0.f; q0 = 0.f; q1 = 0.f; q2 = 0.f; c0 = 0.f; s_cull = 3.0e38f; }

    float cr = colors[3*i+0], cg = colors[3*i+1], cb = colors[3*i+2];
    float v = (lane == 0) ? m2x
            : (lane == 1) ? m2y
            : (lane == 2) ? s_cull
            : (lane == 3) ? q0
            : (lane == 4) ? q1
            : (lane == 5) ? q2
            : (lane == 6) ? c0
            : (lane == 7) ? cr
            : (lane == 8) ? cg
                          : cb;
    if (lane < 10) soa[lane*NGAUSS + rank] = v;
}

// ---------------- render: reg-resident segment, no LDS staging ----------------
// Block = 64x1 px tile, 16 waves split depth into 125-gaussian segments.
// Each lane HOLDS the params of its segment's gaussians (2 chunks x 10 regs,
// stride-1 coalesced SoA loads). Cull on own regs -> ballot -> survivors
// broadcast via v_readlane from holder lane. 16 partials combined in 16KB LDS.
// Reference semantics: weight[0]=a_0; weight[n>=1]=a_n*(1-a_n)*prod_{k<n}(1-a_k)
__global__ __launch_bounds__(1024) void render_fused(
    const float* __restrict__ soa, float* __restrict__ out)
{
    __shared__ float4 pOut[NW*64];

    int tid  = threadIdx.x;
    int lane = tid & 63;
    int w    = tid >> 6;
    int bid  = blockIdx.x;
    int row  = bid >> 1;
    int xoff = (bid & 1) * 64;

    float px = (float)(xoff + lane);
    float py = (float)row;
    float x0 = (float)xoff, x1 = x0 + 63.0f;

    float Cr = 0.f, Cg = 0.f, Cb = 0.f, T = 1.f;

    int segBase = w * SEGSZ;

    // ---- load own-lane params: chunk A (lane 0..63), chunk B (lane 64..124) ----
    int gA = segBase + lane;
    bool vB = (64 + lane) < SEGSZ;
    int gB = vB ? (segBase + 64 + lane) : segBase;
    float A0 = soa[0*NGAUSS+gA], A1 = soa[1*NGAUSS+gA], A2 = soa[2*NGAUSS+gA];
    float A3 = soa[3*NGAUSS+gA], A4 = soa[4*NGAUSS+gA], A5 = soa[5*NGAUSS+gA];
    float A6 = soa[6*NGAUSS+gA], A7 = soa[7*NGAUSS+gA], A8 = soa[8*NGAUSS+gA];
    float A9 = soa[9*NGAUSS+gA];
    float B0 = soa[0*NGAUSS+gB], B1 = soa[1*NGAUSS+gB], B2 = soa[2*NGAUSS+gB];
    float B3 = soa[3*NGAUSS+gB], B4 = soa[4*NGAUSS+gB], B5 = soa[5*NGAUSS+gB];
    float B6 = soa[6*NGAUSS+gB], B7 = soa[7*NGAUSS+gB], B8 = soa[8*NGAUSS+gB];
    float B9 = soa[9*NGAUSS+gB];

    // ---- chunk A ----
    {
        float dxm = fmaxf(0.f, fmaxf(x0 - A0, A0 - x1));
        float dym = fabsf(py - A1);
        bool keep = A2 * fmaf(dxm, dxm, dym*dym) <= 24.f;   // alpha >= c0*2^-24
        unsigned long long mask = __ballot(keep);
        while (mask) {
            int b = __builtin_ctzll(mask);
            mask &= mask - 1;
            int gn = segBase + b;
            float gmx = rdlane(A0,b), gmy = rdlane(A1,b);
            float gq0 = rdlane(A3,b), gq1 = rdlane(A4,b), gq2 = rdlane(A5,b);
            float gc0 = rdlane(A6,b), gcr = rdlane(A7,b);
            float gcg = rdlane(A8,b), gcb = rdlane(A9,b);
            float dy = py - gmy;
            float dx = px - gmx;
            float e  = fmaf(fmaf(gq0, dx, gq1*dy), dx, (gq2*dy)*dy);
            float al = gc0 * exp2f(e);               // alpha
            float wgt = T * al;                      // T*alpha
            float sel = (gn == 0) ? 0.f : al;        // rank-0: weight = alpha exactly
            float f = fmaf(-sel, wgt, wgt);          // T*alpha*(1-alpha)
            Cr = fmaf(f, gcr, Cr);
            Cg = fmaf(f, gcg, Cg);
            Cb = fmaf(f, gcb, Cb);
            T -= wgt;                                // T *= (1-alpha)
        }
    }
    // ---- chunk B ----
    {
        float dxm = fmaxf(0.f, fmaxf(x0 - B0, B0 - x1));
        float dym = fabsf(py - B1);
        bool keep = vB && (B2 * fmaf(dxm, dxm, dym*dym) <= 24.f);
        unsigned long long mask = __ballot(keep);
        while (mask) {
            int b = __builtin_ctzll(mask);
            mask &= mask - 1;
            float gmx = rdlane(B0,b), gmy = rdlane(B1,b);
            float gq0 = rdlane(B3,b), gq1 = rdlane(B4,b), gq2 = rdlane(B5,b);
            float gc0 = rdlane(B6,b), gcr = rdlane(B7,b);
            float gcg = rdlane(B8,b), gcb = rdlane(B9,b);
            float dy = py - gmy;
            float dx = px - gmx;
            float e  = fmaf(fmaf(gq0, dx, gq1*dy), dx, (gq2*dy)*dy);
            float al = gc0 * exp2f(e);
            float wgt = T * al;
            float f = fmaf(-al, wgt, wgt);           // gn>0 always here
            Cr = fmaf(f, gcr, Cr);
            Cg = fmaf(f, gcg, Cg);
            Cb = fmaf(f, gcb, Cb);
            T -= wgt;
        }
    }

    pOut[w*64 + lane] = make_float4(Cr, Cg, Cb, T);
    __syncthreads();

    // ---- wave 0 composites the 16 depth-ordered partials for its 64 px ----
    if (tid < 64) {
        float cR = 0.f, cG = 0.f, cB = 0.f, tA = 1.f;
        #pragma unroll
        for (int s = 0; s < NW; ++s) {
            float4 v = pOut[s*64 + tid];
            cR = fmaf(tA, v.x, cR);
            cG = fmaf(tA, v.y, cG);
            cB = fmaf(tA, v.z, cB);
            tA *= v.w;
        }
        int p = row*IMW + xoff + tid;
        out[3*p+0] = cR; out[3*p+1] = cG; out[3*p+2] = cB;
    }
}

extern "C" void kernel_launch(void* const* d_in, const int* in_sizes, int n_in,
                              void* d_out, int out_size, void* d_ws, size_t ws_size,
                              hipStream_t stream)
{
    const float* means3D = (const float*)d_in[0];
    const float* covs3d  = (const float*)d_in[1];
    const float* colors  = (const float*)d_in[2];
    const float* opac    = (const float*)d_in[3];
    const float* Km      = (const float*)d_in[4];
    const float* Rm      = (const float*)d_in[5];
    const float* tv      = (const float*)d_in[6];

    float* soa = (float*)d_ws;   // 10 arrays x NGAUSS floats = 80 KB

    preprank_kernel<<<PREPBLK, 1024, 0, stream>>>(
        means3D, covs3d, colors, opac, Km, Rm, tv, soa);
    render_fused<<<NPIX/64, 1024, 0, stream>>>(soa, (float*)d_out);
}